// Round 1
// baseline (476.364 us; speedup 1.0000x reference)
//
#include <hip/hip_runtime.h>
#include <stdint.h>

typedef __attribute__((ext_vector_type(8))) short bf16x8;
typedef __attribute__((ext_vector_type(4))) float f32x4;

#define BB 4
#define NH 16
#define TT 2048
#define HD 64
#define CC 1024

__device__ __forceinline__ unsigned short f2bf(float f) {
  unsigned int u = __builtin_bit_cast(unsigned int, f);
  u += 0x7fff + ((u >> 16) & 1);
  return (unsigned short)(u >> 16);
}

__device__ __forceinline__ void g2l16(const void* g, void* s) {
  __builtin_amdgcn_global_load_lds(
      (const __attribute__((address_space(1))) unsigned int*)g,
      (__attribute__((address_space(3))) unsigned int*)s, 16, 0, 0);
}

// ---------------- cast f32 -> bf16 (vectorized) ----------------
__global__ __launch_bounds__(256) void cast_f32_to_bf16(
    const float* __restrict__ in, unsigned short* __restrict__ out, int n) {
  int i = (blockIdx.x * 256 + threadIdx.x) * 4;
  if (i >= n) return;
  float4 v = *(const float4*)(in + i);
  ushort4 o;
  o.x = f2bf(v.x); o.y = f2bf(v.y); o.z = f2bf(v.z); o.w = f2bf(v.w);
  *(ushort4*)(out + i) = o;
}

// ---------------- weight transpose + cast: w[K][N] f32 -> wt[N][K] bf16 ----
__global__ __launch_bounds__(256) void transpose_cast_w(
    const float* __restrict__ w, unsigned short* __restrict__ wt) {
  __shared__ float tile[32][33];
  int nb = blockIdx.x * 32, kb = blockIdx.y * 32;
  int tx = threadIdx.x, ty = threadIdx.y;
#pragma unroll
  for (int r = ty; r < 32; r += 8)
    tile[r][tx] = w[(size_t)(kb + r) * CC + nb + tx];
  __syncthreads();
#pragma unroll
  for (int r = ty; r < 32; r += 8)
    wt[(size_t)(nb + r) * CC + kb + tx] = f2bf(tile[tx][r]);
}

// ---------------- GEMM: C[M][N] = A[M][K] @ Bt[N][K]^T + bias ----------------
// MODE 0: out bf16 scattered into (B,H,T,D) layout, scaled.
// MODE 1: out f32 row-major [M][N].
template <int MODE>
__global__ __launch_bounds__(256) void gemm_bt(
    const unsigned short* __restrict__ A, const unsigned short* __restrict__ Bt,
    const float* __restrict__ bias, void* __restrict__ Out,
    int M, int N, int Kd, float scale) {
  __shared__ unsigned short As[128 * 32];
  __shared__ unsigned short Bs[128 * 32];
  const int t = threadIdx.x, l = t & 63, w = t >> 6;
  const int lr = l & 15, lg = l >> 4;
  const int m0 = blockIdx.y * 128, n0 = blockIdx.x * 128;
  const int wr = w >> 1, wc = w & 1;
  f32x4 acc[4][4] = {};
  for (int k0 = 0; k0 < Kd; k0 += 32) {
#pragma unroll
    for (int i = 0; i < 2; ++i) {
      int c = w * 64 + l + i * 256;      // 512 chunks of 16B per 8KB tile
      int row = c >> 2, cb = (c & 3) * 8;
      g2l16(A + (size_t)(m0 + row) * Kd + k0 + cb, (char*)As + c * 16);
      g2l16(Bt + (size_t)(n0 + row) * Kd + k0 + cb, (char*)Bs + c * 16);
    }
    __syncthreads();
    bf16x8 af[4], bfr[4];
#pragma unroll
    for (int mi = 0; mi < 4; ++mi)
      af[mi] = *(const bf16x8*)(As + (wr * 64 + mi * 16 + lr) * 32 + lg * 8);
#pragma unroll
    for (int nj = 0; nj < 4; ++nj)
      bfr[nj] = *(const bf16x8*)(Bs + (wc * 64 + nj * 16 + lr) * 32 + lg * 8);
#pragma unroll
    for (int mi = 0; mi < 4; ++mi)
#pragma unroll
      for (int nj = 0; nj < 4; ++nj)
        acc[mi][nj] = __builtin_amdgcn_mfma_f32_16x16x32_bf16(
            af[mi], bfr[nj], acc[mi][nj], 0, 0, 0);
    __syncthreads();
  }
#pragma unroll
  for (int mi = 0; mi < 4; ++mi) {
#pragma unroll
    for (int nj = 0; nj < 4; ++nj) {
      int col = n0 + wc * 64 + nj * 16 + lr;
      float bv = bias[col];
#pragma unroll
      for (int j = 0; j < 4; ++j) {
        int rowm = m0 + wr * 64 + mi * 16 + lg * 4 + j;
        float v = (acc[mi][nj][j] + bv) * scale;
        if (MODE == 0) {
          int b_ = rowm >> 11, tq = rowm & (TT - 1);
          int h_ = col >> 6, d_ = col & (HD - 1);
          ((unsigned short*)Out)[((size_t)((b_ * NH + h_) * TT + tq) << 6) + d_] =
              f2bf(v);
        } else {
          ((float*)Out)[(size_t)rowm * N + col] = v;
        }
      }
    }
  }
}

// ---------------- flash attention ----------------
// Q,K,V: bf16 [B*H][T][64]; mask int32 [B][T]; O: bf16 [B*T][C] (b,t,h*64+d)
__global__ __launch_bounds__(256) void attn_fwd(
    const unsigned short* __restrict__ Q, const unsigned short* __restrict__ K,
    const unsigned short* __restrict__ V, const int* __restrict__ mask,
    unsigned short* __restrict__ O) {
  __shared__ char Kl[64 * 128];      // [key][d] swizzled
  __shared__ char Vl[64 * 128];      // [d][key] (transposed) swizzled
  __shared__ char Pl[4][16 * 128];   // per-wave [q][key] swizzled
  const int t = threadIdx.x, l = t & 63, w = t >> 6;
  const int lr = l & 15, lg = l >> 4;
  const int bh = blockIdx.y;
  const int b_ = bh >> 4, h_ = bh & (NH - 1);
  const int q0 = blockIdx.x * 64 + w * 16;
  const size_t base = (size_t)bh * TT * HD;

  bf16x8 qf[2];
#pragma unroll
  for (int hf = 0; hf < 2; ++hf)
    qf[hf] = *(const bf16x8*)(Q + base + (size_t)(q0 + lr) * HD + hf * 32 + lg * 8);

  f32x4 o_[4] = {};
  float Mr[4], Lr[4];
#pragma unroll
  for (int j = 0; j < 4; ++j) { Mr[j] = -INFINITY; Lr[j] = 0.f; }
  const int* mrow = mask + b_ * TT;

  for (int kt = 0; kt < TT / 64; ++kt) {
    __syncthreads();
    // stage K (row-major swizzled) and V (transposed swizzled)
#pragma unroll
    for (int i = 0; i < 2; ++i) {
      int c = t + i * 256;
      int row = c >> 3, cb8 = c & 7;
      int4 kv = *(const int4*)(K + base + (size_t)(kt * 64 + row) * HD + cb8 * 8);
      *(int4*)(Kl + row * 128 + ((cb8 * 16) ^ ((row & 7) << 4))) = kv;
      int4 vv = *(const int4*)(V + base + (size_t)(kt * 64 + row) * HD + cb8 * 8);
      const unsigned short* pv = (const unsigned short*)&vv;
#pragma unroll
      for (int jj = 0; jj < 8; ++jj) {
        int d = cb8 * 8 + jj;
        *(unsigned short*)(Vl + d * 128 + ((row * 2) ^ ((d & 7) << 4))) = pv[jj];
      }
    }
    __syncthreads();

    // S = Q K^T  (pre-scaled Q carries 1/sqrt(64))
    f32x4 s[4];
#pragma unroll
    for (int sub = 0; sub < 4; ++sub) {
      f32x4 z = {};
      s[sub] = z;
#pragma unroll
      for (int hf = 0; hf < 2; ++hf) {
        int key = lr + 16 * sub;
        bf16x8 kf = *(const bf16x8*)(
            Kl + key * 128 + ((lg * 16 + hf * 64) ^ ((key & 7) << 4)));
        s[sub] = __builtin_amdgcn_mfma_f32_16x16x32_bf16(qf[hf], kf, s[sub], 0, 0, 0);
      }
      int kglob = kt * 64 + 16 * sub + lr;
      if (mrow[kglob] == 0) {
        s[sub][0] = -1e10f; s[sub][1] = -1e10f; s[sub][2] = -1e10f; s[sub][3] = -1e10f;
      }
    }

    // online softmax (rows = lg*4+j, cols across lr lanes)
    float pr[4][4];
    float rs[4];
#pragma unroll
    for (int j = 0; j < 4; ++j) {
      float tm = fmaxf(fmaxf(s[0][j], s[1][j]), fmaxf(s[2][j], s[3][j]));
#pragma unroll
      for (int mk = 1; mk <= 8; mk <<= 1) tm = fmaxf(tm, __shfl_xor(tm, mk));
      float nm = fmaxf(Mr[j], tm);
      float r = __expf(Mr[j] - nm);
      Mr[j] = nm;
      float ps = 0.f;
#pragma unroll
      for (int sub = 0; sub < 4; ++sub) {
        float p = __expf(s[sub][j] - nm);
        pr[sub][j] = p;
        ps += p;
      }
#pragma unroll
      for (int mk = 1; mk <= 8; mk <<= 1) ps += __shfl_xor(ps, mk);
      Lr[j] = Lr[j] * r + ps;
      rs[j] = r;
    }
#pragma unroll
    for (int ds = 0; ds < 4; ++ds) {
      o_[ds][0] *= rs[0]; o_[ds][1] *= rs[1];
      o_[ds][2] *= rs[2]; o_[ds][3] *= rs[3];
    }

    // P -> per-wave LDS (bf16, swizzled)
#pragma unroll
    for (int sub = 0; sub < 4; ++sub)
#pragma unroll
      for (int j = 0; j < 4; ++j) {
        int r_ = lg * 4 + j, col = sub * 16 + lr;
        *(unsigned short*)(Pl[w] + r_ * 128 + ((col * 2) ^ ((r_ & 7) << 4))) =
            f2bf(pr[sub][j]);
      }
    __syncthreads();

    // O += P V
#pragma unroll
    for (int ks = 0; ks < 2; ++ks) {
      bf16x8 pa = *(const bf16x8*)(
          Pl[w] + lr * 128 + ((lg * 16 + ks * 64) ^ ((lr & 7) << 4)));
#pragma unroll
      for (int ds = 0; ds < 4; ++ds) {
        int d = lr + 16 * ds;
        bf16x8 vf = *(const bf16x8*)(
            Vl + d * 128 + ((lg * 16 + ks * 64) ^ ((d & 7) << 4)));
        o_[ds] = __builtin_amdgcn_mfma_f32_16x16x32_bf16(pa, vf, o_[ds], 0, 0, 0);
      }
    }
  }

  // epilogue: O/L -> bf16 (B,T,H*D)
#pragma unroll
  for (int j = 0; j < 4; ++j) {
    float inv = 1.f / Lr[j];
    int qg = q0 + lg * 4 + j;
    size_t orow = ((size_t)(b_ * TT) + qg) * CC + h_ * 64;
#pragma unroll
    for (int ds = 0; ds < 4; ++ds)
      O[orow + lr + 16 * ds] = f2bf(o_[ds][j] * inv);
  }
}

extern "C" void kernel_launch(void* const* d_in, const int* in_sizes, int n_in,
                              void* d_out, int out_size, void* d_ws, size_t ws_size,
                              hipStream_t stream) {
  const float* x  = (const float*)d_in[0];
  const float* ft = (const float*)d_in[1];
  const int* mask = (const int*)d_in[2];
  const float* wq = (const float*)d_in[3];
  const float* bq = (const float*)d_in[4];
  const float* wk = (const float*)d_in[5];
  const float* bk = (const float*)d_in[6];
  const float* wv = (const float*)d_in[7];
  const float* bv = (const float*)d_in[8];
  const float* wo = (const float*)d_in[9];
  const float* bo = (const float*)d_in[10];
  float* out = (float*)d_out;

  // workspace layout (~109 MB)
  char* ws = (char*)d_ws;
  const size_t NTOK = (size_t)BB * TT;   // 8192
  const size_t SB = NTOK * CC * 2;       // 16 MiB
  unsigned short* xb  = (unsigned short*)ws; ws += SB;
  unsigned short* fb  = (unsigned short*)ws; ws += SB;
  unsigned short* Qb  = (unsigned short*)ws; ws += SB;
  unsigned short* Kb  = (unsigned short*)ws; ws += SB;
  unsigned short* Vb  = (unsigned short*)ws; ws += SB;
  unsigned short* AO  = (unsigned short*)ws; ws += SB;
  unsigned short* wqt = (unsigned short*)ws; ws += (size_t)CC * CC * 2;
  unsigned short* wkt = (unsigned short*)ws; ws += (size_t)CC * CC * 2;
  unsigned short* wvt = (unsigned short*)ws; ws += (size_t)CC * CC * 2;
  unsigned short* wot = (unsigned short*)ws; ws += (size_t)CC * CC * 2;

  int ncast = (int)(NTOK * CC);
  cast_f32_to_bf16<<<ncast / 4 / 256, 256, 0, stream>>>(x, xb, ncast);
  cast_f32_to_bf16<<<ncast / 4 / 256, 256, 0, stream>>>(ft, fb, ncast);
  dim3 tb(32, 8), tg(32, 32);
  transpose_cast_w<<<tg, tb, 0, stream>>>(wq, wqt);
  transpose_cast_w<<<tg, tb, 0, stream>>>(wk, wkt);
  transpose_cast_w<<<tg, tb, 0, stream>>>(wv, wvt);
  transpose_cast_w<<<tg, tb, 0, stream>>>(wo, wot);

  dim3 gp(CC / 128, NTOK / 128);  // (8, 64)
  gemm_bt<0><<<gp, 256, 0, stream>>>(xb, wqt, bq, Qb, (int)NTOK, CC, CC, 0.125f);
  gemm_bt<0><<<gp, 256, 0, stream>>>(fb, wkt, bk, Kb, (int)NTOK, CC, CC, 1.0f);
  gemm_bt<0><<<gp, 256, 0, stream>>>(fb, wvt, bv, Vb, (int)NTOK, CC, CC, 1.0f);

  dim3 ga(TT / 64, BB * NH);  // (32, 64)
  attn_fwd<<<ga, 256, 0, stream>>>(Qb, Kb, Vb, mask, AO);

  gemm_bt<1><<<gp, 256, 0, stream>>>(AO, wot, bo, out, (int)NTOK, CC, CC, 1.0f);
}

// Round 2
// 430.471 us; speedup vs baseline: 1.1066x; 1.1066x over previous
//
#include <hip/hip_runtime.h>
#include <stdint.h>

typedef __attribute__((ext_vector_type(8))) short bf16x8;
typedef __attribute__((ext_vector_type(4))) float f32x4;
typedef __attribute__((ext_vector_type(16))) float f32x16;

#define BB 4
#define NH 16
#define TT 2048
#define HD 64
#define CC 1024

__device__ __forceinline__ unsigned short f2bf(float f) {
  unsigned int u = __builtin_bit_cast(unsigned int, f);
  u += 0x7fff + ((u >> 16) & 1);
  return (unsigned short)(u >> 16);
}

__device__ __forceinline__ float fast_exp2(float x) {
#if __has_builtin(__builtin_amdgcn_exp2f)
  return __builtin_amdgcn_exp2f(x);
#else
  return exp2f(x);
#endif
}

__device__ __forceinline__ unsigned int cvtpk(float lo, float hi) {
  unsigned int r;
  asm("v_cvt_pk_bf16_f32 %0, %1, %2" : "=v"(r) : "v"(lo), "v"(hi));
  return r;
}

// swap: a' = (l<32? a : b_partner)  [pa low words]
//       b' = (l<32? a_partner : b)  [pa high words]
__device__ __forceinline__ void plswap(unsigned int& a, unsigned int& b) {
#if __has_builtin(__builtin_amdgcn_permlane32_swap)
  auto r = __builtin_amdgcn_permlane32_swap(a, b, false, false);
  a = r[0];
  b = r[1];
#else
  unsigned int as = __shfl_xor((int)a, 32), bs = __shfl_xor((int)b, 32);
  bool hi = (threadIdx.x & 32) != 0;
  unsigned int na = hi ? bs : a;
  unsigned int nb = hi ? b : as;
  a = na; b = nb;
#endif
}

__device__ __forceinline__ void g2l16(const void* g, void* s) {
  __builtin_amdgcn_global_load_lds(
      (const __attribute__((address_space(1))) unsigned int*)g,
      (__attribute__((address_space(3))) unsigned int*)s, 16, 0, 0);
}

// ---------------- cast f32 -> bf16 ----------------
__global__ __launch_bounds__(256) void cast_f32_to_bf16(
    const float* __restrict__ in, unsigned short* __restrict__ out, int n) {
  int i = (blockIdx.x * 256 + threadIdx.x) * 4;
  if (i >= n) return;
  float4 v = *(const float4*)(in + i);
  ushort4 o;
  o.x = f2bf(v.x); o.y = f2bf(v.y); o.z = f2bf(v.z); o.w = f2bf(v.w);
  *(ushort4*)(out + i) = o;
}

// ---------------- mask -> float bias (log2e-folded) ----------------
__global__ __launch_bounds__(256) void make_fmask(
    const int* __restrict__ mask, float* __restrict__ fm, int n) {
  int i = blockIdx.x * 256 + threadIdx.x;
  if (i < n) fm[i] = mask[i] ? 0.f : -1.44269504e10f;
}

// ---------------- weight transpose+cast: w[K][N] f32 -> wt[N][K] bf16 ------
__global__ __launch_bounds__(256) void transpose_cast_w(
    const float* __restrict__ w, unsigned short* __restrict__ wt) {
  __shared__ float tile[32][33];
  int nb = blockIdx.x * 32, kb = blockIdx.y * 32;
  int tx = threadIdx.x, ty = threadIdx.y;
#pragma unroll
  for (int r = ty; r < 32; r += 8)
    tile[r][tx] = w[(size_t)(kb + r) * CC + nb + tx];
  __syncthreads();
#pragma unroll
  for (int r = ty; r < 32; r += 8)
    wt[(size_t)(nb + r) * CC + kb + tx] = f2bf(tile[tx][r]);
}

// ---------------- V transpose: Vb[bh][t][d] -> Vt[bh][d][t] ----------------
__global__ __launch_bounds__(256) void transpose_v(
    const unsigned short* __restrict__ Vb, unsigned short* __restrict__ Vt) {
  __shared__ unsigned short tile[64][72];
  const int bh = blockIdx.y, t0 = blockIdx.x * 64, tid = threadIdx.x;
  const size_t ibase = (size_t)bh * TT * HD;
#pragma unroll
  for (int i = 0; i < 2; ++i) {
    int c = tid + i * 256;
    int r = c >> 3, c8 = c & 7;
    *(int4*)&tile[r][c8 * 8] =
        *(const int4*)(Vb + ibase + (size_t)(t0 + r) * HD + c8 * 8);
  }
  __syncthreads();
  const size_t obase = (size_t)bh * HD * TT;
#pragma unroll
  for (int i = 0; i < 2; ++i) {
    int c = tid + i * 256;
    int d = c >> 3, c8 = c & 7;
    unsigned short v[8];
#pragma unroll
    for (int j = 0; j < 8; ++j) v[j] = tile[c8 * 8 + j][d];
    *(int4*)(Vt + obase + (size_t)d * TT + t0 + c8 * 8) = *(int4*)v;
  }
}

// ---------------- GEMM: C[M][N] = A[M][K] @ Bt[N][K]^T + bias --------------
template <int MODE>
__global__ __launch_bounds__(256) void gemm_bt(
    const unsigned short* __restrict__ A, const unsigned short* __restrict__ Bt,
    const float* __restrict__ bias, void* __restrict__ Out,
    int M, int N, int Kd, float scale) {
  __shared__ unsigned short As[128 * 32];
  __shared__ unsigned short Bs[128 * 32];
  const int t = threadIdx.x, l = t & 63, w = t >> 6;
  const int lr = l & 15, lg = l >> 4;
  const int m0 = blockIdx.y * 128, n0 = blockIdx.x * 128;
  const int wr = w >> 1, wc = w & 1;
  f32x4 acc[4][4] = {};
  for (int k0 = 0; k0 < Kd; k0 += 32) {
#pragma unroll
    for (int i = 0; i < 2; ++i) {
      int c = w * 64 + l + i * 256;
      int row = c >> 2, cb = (c & 3) * 8;
      g2l16(A + (size_t)(m0 + row) * Kd + k0 + cb, (char*)As + c * 16);
      g2l16(Bt + (size_t)(n0 + row) * Kd + k0 + cb, (char*)Bs + c * 16);
    }
    __syncthreads();
    bf16x8 af[4], bfr[4];
#pragma unroll
    for (int mi = 0; mi < 4; ++mi)
      af[mi] = *(const bf16x8*)(As + (wr * 64 + mi * 16 + lr) * 32 + lg * 8);
#pragma unroll
    for (int nj = 0; nj < 4; ++nj)
      bfr[nj] = *(const bf16x8*)(Bs + (wc * 64 + nj * 16 + lr) * 32 + lg * 8);
#pragma unroll
    for (int mi = 0; mi < 4; ++mi)
#pragma unroll
      for (int nj = 0; nj < 4; ++nj)
        acc[mi][nj] = __builtin_amdgcn_mfma_f32_16x16x32_bf16(
            af[mi], bfr[nj], acc[mi][nj], 0, 0, 0);
    __syncthreads();
  }
#pragma unroll
  for (int mi = 0; mi < 4; ++mi) {
#pragma unroll
    for (int nj = 0; nj < 4; ++nj) {
      int col = n0 + wc * 64 + nj * 16 + lr;
      float bv = bias[col];
#pragma unroll
      for (int j = 0; j < 4; ++j) {
        int rowm = m0 + wr * 64 + mi * 16 + lg * 4 + j;
        float v = (acc[mi][nj][j] + bv) * scale;
        if (MODE == 0) {
          int b_ = rowm >> 11, tq = rowm & (TT - 1);
          int h_ = col >> 6, d_ = col & (HD - 1);
          ((unsigned short*)Out)[((size_t)((b_ * NH + h_) * TT + tq) << 6) + d_] =
              f2bf(v);
        } else {
          ((float*)Out)[(size_t)rowm * N + col] = v;
        }
      }
    }
  }
}

// ---------------- flash attention, swapped-operand 32x32, no LDS -----------
// Q,K: bf16 [B*H][T][64]; Vt: bf16 [B*H][64][T]; fm: f32 [B][T];
// O: bf16 [B*T][C] at (b,t,h*64+d)
__global__ __launch_bounds__(256) void attn_fwd2(
    const unsigned short* __restrict__ Q, const unsigned short* __restrict__ K,
    const unsigned short* __restrict__ Vt, const float* __restrict__ fm,
    unsigned short* __restrict__ O) {
  const int t = threadIdx.x, l = t & 63, w = t >> 6;
  const int q5 = l & 31, hi = l >> 5;
  const int bh = blockIdx.y, b_ = bh >> 4, h_ = bh & (NH - 1);
  const int q = blockIdx.x * 128 + w * 32 + q5;
  const size_t base = (size_t)bh * TT * HD;

  // Q fragments: qf[dk][b] = Q[q][dk*16 + 8*hi + b]  (B-operand: Q^T)
  bf16x8 qf[4];
  {
    const unsigned short* qp = Q + base + (size_t)q * HD + 8 * hi;
#pragma unroll
    for (int dk = 0; dk < 4; ++dk) qf[dk] = *(const bf16x8*)(qp + dk * 16);
  }
  f32x16 ot[2];
#pragma unroll
  for (int i = 0; i < 16; ++i) { ot[0][i] = 0.f; ot[1][i] = 0.f; }
  float m_ = -3.0e38f, l_ = 0.f;
  const float* fmr = fm + b_ * TT;
  const unsigned short* kp = K + base + 8 * hi;
  const unsigned short* vp = Vt + (size_t)bh * HD * TT;

  for (int kt = 0; kt < TT / 64; ++kt) {
    const int kb = kt * 64;
    // S^T = K @ Q^T, C-init = mask bias. Lane holds col=q, rows
    // k = kk*32 + (reg&3) + 8*(reg>>2) + 4*hi.
    f32x16 s[2];
#pragma unroll
    for (int kk = 0; kk < 2; ++kk) {
#pragma unroll
      for (int g = 0; g < 4; ++g) {
        float4 mv = *(const float4*)(fmr + kb + kk * 32 + g * 8 + 4 * hi);
        s[kk][4 * g + 0] = mv.x; s[kk][4 * g + 1] = mv.y;
        s[kk][4 * g + 2] = mv.z; s[kk][4 * g + 3] = mv.w;
      }
    }
#pragma unroll
    for (int kk = 0; kk < 2; ++kk) {
      const unsigned short* krow = kp + (size_t)(kb + kk * 32 + q5) * HD;
#pragma unroll
      for (int dk = 0; dk < 4; ++dk) {
        bf16x8 kf = *(const bf16x8*)(krow + dk * 16);
        s[kk] = __builtin_amdgcn_mfma_f32_32x32x16_bf16(kf, qf[dk], s[kk], 0, 0, 0);
      }
    }
    // online softmax (base-2; scale folded into Q); pair lanes l,l^32 share q
    float tm = s[0][0];
#pragma unroll
    for (int i = 1; i < 16; ++i) tm = fmaxf(tm, s[0][i]);
#pragma unroll
    for (int i = 0; i < 16; ++i) tm = fmaxf(tm, s[1][i]);
    tm = fmaxf(tm, __shfl_xor(tm, 32));
    const bool resc = !__all(tm <= m_ + 8.f);   // defer-max THR=8
    const float nm = resc ? fmaxf(m_, tm) : m_;
    float ps = 0.f;
#pragma unroll
    for (int kk = 0; kk < 2; ++kk)
#pragma unroll
      for (int i = 0; i < 16; ++i) {
        float p = fast_exp2(s[kk][i] - nm);
        s[kk][i] = p;
        ps += p;
      }
    ps += __shfl_xor(ps, 32);
    if (resc) {
      float r = fast_exp2(m_ - nm);
      l_ = l_ * r + ps;
#pragma unroll
      for (int i = 0; i < 16; ++i) { ot[0][i] *= r; ot[1][i] *= r; }
      m_ = nm;
    } else {
      l_ += ps;
    }

    // P -> bf16 pa[ks] fragments in-register (cvt_pk + permlane32_swap):
    // pa[ks][b] = P[q][ks*16 + 8*hi + b]
    unsigned int wl[2][4], wh[2][4];
#pragma unroll
    for (int kk = 0; kk < 2; ++kk)
#pragma unroll
      for (int g = 0; g < 4; ++g) {
        wl[kk][g] = cvtpk(s[kk][4 * g + 0], s[kk][4 * g + 1]);
        wh[kk][g] = cvtpk(s[kk][4 * g + 2], s[kk][4 * g + 3]);
      }
    bf16x8 pa[4];
#pragma unroll
    for (int ks = 0; ks < 4; ++ks) {
      const int kk = ks >> 1, gA = 2 * (ks & 1), gB = gA + 1;
      unsigned int a0 = wl[kk][gA], b0 = wl[kk][gB];
      unsigned int a1 = wh[kk][gA], b1 = wh[kk][gB];
      plswap(a0, b0);  // a0 -> k+{0,1}, b0 -> k+{4,5}
      plswap(a1, b1);  // a1 -> k+{2,3}, b1 -> k+{6,7}
      unsigned int pw[4] = {a0, a1, b0, b1};
      pa[ks] = *(bf16x8*)pw;
    }

    // O^T += V^T @ P^T : A = Vt[d][k] contiguous
#pragma unroll
    for (int dt = 0; dt < 2; ++dt) {
      const unsigned short* vrow = vp + (size_t)(dt * 32 + q5) * TT + kb + 8 * hi;
#pragma unroll
      for (int ks = 0; ks < 4; ++ks) {
        bf16x8 vf = *(const bf16x8*)(vrow + ks * 16);
        ot[dt] = __builtin_amdgcn_mfma_f32_32x32x16_bf16(vf, pa[ks], ot[dt], 0, 0, 0);
      }
    }
  }

  // epilogue: lane holds col q, rows d = dt*32 + 8g + 4hi + j
  const float inv = 1.f / l_;
  unsigned short* orow = O + ((size_t)(b_ * TT) + q) * CC + h_ * 64 + 4 * hi;
#pragma unroll
  for (int dt = 0; dt < 2; ++dt)
#pragma unroll
    for (int g = 0; g < 4; ++g) {
      unsigned short pk4[4];
#pragma unroll
      for (int j = 0; j < 4; ++j) pk4[j] = f2bf(ot[dt][4 * g + j] * inv);
      *(ushort4*)(orow + dt * 32 + 8 * g) = *(ushort4*)pk4;
    }
}

extern "C" void kernel_launch(void* const* d_in, const int* in_sizes, int n_in,
                              void* d_out, int out_size, void* d_ws, size_t ws_size,
                              hipStream_t stream) {
  const float* x  = (const float*)d_in[0];
  const float* ft = (const float*)d_in[1];
  const int* mask = (const int*)d_in[2];
  const float* wq = (const float*)d_in[3];
  const float* bq = (const float*)d_in[4];
  const float* wk = (const float*)d_in[5];
  const float* bk = (const float*)d_in[6];
  const float* wv = (const float*)d_in[7];
  const float* bv = (const float*)d_in[8];
  const float* wo = (const float*)d_in[9];
  const float* bo = (const float*)d_in[10];
  float* out = (float*)d_out;

  char* ws = (char*)d_ws;
  const size_t NTOK = (size_t)BB * TT;   // 8192
  const size_t SB = NTOK * CC * 2;       // 16 MiB
  unsigned short* xb  = (unsigned short*)ws; ws += SB;  // reused as Vt later
  unsigned short* fb  = (unsigned short*)ws; ws += SB;
  unsigned short* Qb  = (unsigned short*)ws; ws += SB;
  unsigned short* Kb  = (unsigned short*)ws; ws += SB;
  unsigned short* Vb  = (unsigned short*)ws; ws += SB;
  unsigned short* AO  = (unsigned short*)ws; ws += SB;
  unsigned short* wqt = (unsigned short*)ws; ws += (size_t)CC * CC * 2;
  unsigned short* wkt = (unsigned short*)ws; ws += (size_t)CC * CC * 2;
  unsigned short* wvt = (unsigned short*)ws; ws += (size_t)CC * CC * 2;
  unsigned short* wot = (unsigned short*)ws; ws += (size_t)CC * CC * 2;
  float* fmk = (float*)ws; ws += NTOK * 4;
  unsigned short* Vtb = xb;  // alias: xb dead after Q GEMM

  int ncast = (int)(NTOK * CC);
  cast_f32_to_bf16<<<ncast / 4 / 256, 256, 0, stream>>>(x, xb, ncast);
  cast_f32_to_bf16<<<ncast / 4 / 256, 256, 0, stream>>>(ft, fb, ncast);
  dim3 tb(32, 8), tg(32, 32);
  transpose_cast_w<<<tg, tb, 0, stream>>>(wq, wqt);
  transpose_cast_w<<<tg, tb, 0, stream>>>(wk, wkt);
  transpose_cast_w<<<tg, tb, 0, stream>>>(wv, wvt);
  transpose_cast_w<<<tg, tb, 0, stream>>>(wo, wot);
  make_fmask<<<(int)(NTOK / 256), 256, 0, stream>>>(mask, fmk, (int)NTOK);

  dim3 gp(CC / 128, NTOK / 128);  // (8, 64)
  const float qscale = 0.125f * 1.44269504f;  // 1/sqrt(64) * log2(e)
  gemm_bt<0><<<gp, 256, 0, stream>>>(xb, wqt, bq, Qb, (int)NTOK, CC, CC, qscale);
  gemm_bt<0><<<gp, 256, 0, stream>>>(fb, wkt, bk, Kb, (int)NTOK, CC, CC, 1.0f);
  gemm_bt<0><<<gp, 256, 0, stream>>>(fb, wvt, bv, Vb, (int)NTOK, CC, CC, 1.0f);

  dim3 gt(TT / 64, BB * NH);  // (32, 64)
  transpose_v<<<gt, 256, 0, stream>>>(Vb, Vtb);

  dim3 ga(TT / 128, BB * NH);  // (16, 64)
  attn_fwd2<<<ga, 256, 0, stream>>>(Qb, Kb, Vtb, fmk, AO);

  gemm_bt<1><<<gp, 256, 0, stream>>>(AO, wot, bo, out, (int)NTOK, CC, CC, 1.0f);
}